// Round 17
// baseline (302.739 us; speedup 1.0000x reference)
//
#include <hip/hip_runtime.h>
#include <hip/hip_fp16.h>
#include <stdint.h>

// MultiResolutionHashEncoding — R17: stripe-pipelined gather∥transpose.
//
// R16: 274us = gather 160 (L2-request-bound, VALUBusy 8.7%) + transpose
//   ~110 (streaming ~3.7TB/s) + boundary. DIFFERENT resources -> overlap.
// R17: S=4 point-stripes; launch i = gather(stripe i) + transpose(stripe
//   i-1) in one kernel, split by blockIdx. First G blocks (G%8==0) keep
//   the bid%8 XCD-class gather structure; rest transpose. 5 launches.
//   NT output stores keep transpose writes out of L2 (no table eviction);
//   coarse-gather L2 pressure accepted (R14/R15: misses cost no time).
// Diagnostic: interior dur <= 0.75*(L0+L4) => overlap real; ~1.0 =>
//   revert to R16 + test regular transpose stores.

#define TPB 256

typedef float vfloat4 __attribute__((ext_vector_type(4)));
typedef float vfloat2 __attribute__((ext_vector_type(2)));

__device__ __forceinline__ uint32_t hash_idx(float cx, float cy, float cz,
                                             int resi, int siz)
{
    const float rf = (float)resi;
    const int x = (int)floorf(cx * rf);
    const int y = (int)floorf(cy * rf);
    const int z = (int)floorf(cz * rf);
    // int32 wraparound multiplies + xor (uint32 = UB-free)
    const uint32_t h = (uint32_t)x * 73856093u
                     ^ (uint32_t)y * 19349663u
                     ^ (uint32_t)z * 83492791u;
    const int32_t hs = (int32_t)h;
    if (siz == (1 << 19)) {
        // numpy abs(INT_MIN)=INT_MIN; python-mod 2^19 == mask
        const uint32_t a = (hs < 0) ? (0u - h) : h;
        return a & 0x7FFFFu;
    } else {
        int32_t a = (hs < 0) ? (int32_t)(0u - h) : hs;
        int32_t r = a % siz;          // compile-time divisor -> magic mul
        if (r < 0) r += siz;
        return (uint32_t)r;
    }
}

__device__ __forceinline__ uint32_t pack_h2(float a, float b)
{
    const __half ha = __float2half_rn(a);
    const __half hb = __float2half_rn(b);
    return (uint32_t)__half_as_ushort(ha)
         | ((uint32_t)__half_as_ushort(hb) << 16);
}

__device__ __forceinline__ vfloat2 unpack_h2(uint32_t v)
{
    vfloat2 r;
    r.x = __half2float(__ushort_as_half((uint16_t)(v & 0xFFFFu)));
    r.y = __half2float(__ushort_as_half((uint16_t)(v >> 16)));
    return r;
}

#define RESI_LIST {16, 22, 30, 42, 58, 80, 111, 153, \
                   212, 294, 406, 561, 776, 1072, 1482, 2048}
#define SIZ_LIST  {4096, 10648, 27000, 74088, 195112, 512000, \
                   524288, 524288, 524288, 524288, 524288, \
                   524288, 524288, 524288, 524288, 524288}

// ---- compile-time per-level gather body: GLOBAL point-block pb ------------
template<int LV>
__device__ __forceinline__ void gather_body(
    const float* __restrict__ coords,
    const float* __restrict__ tables,
    uint32_t* __restrict__ ws,
    int npts, long long pb, int t)
{
    constexpr int RESI[16] = RESI_LIST;
    constexpr int SIZ[16] = SIZ_LIST;

    const long long base = pb * 2048;
    const float* tab = tables + ((size_t)LV << 20);

    uint32_t g[8];
#pragma unroll
    for (int j = 0; j < 8; ++j) {
        const long long p = base + j * 256 + t;
        const float cx = coords[3 * p + 0];   // regular loads (R15 lesson)
        const float cy = coords[3 * p + 1];
        const float cz = coords[3 * p + 2];
        const uint32_t idx = hash_idx(cx, cy, cz, RESI[LV], SIZ[LV]);
        const vfloat2 f = *reinterpret_cast<const vfloat2*>(
            tab + ((size_t)idx << 1));
        g[j] = pack_h2(f.x, f.y);
    }
    uint32_t* wl = ws + (size_t)(LV - 5) * npts + base;
#pragma unroll
    for (int j = 0; j < 8; ++j)   // NT: don't evict the L2-hot table
        __builtin_nontemporal_store(g[j], wl + j * 256 + t);
}

// ---- pipelined kernel: gather stripe gs ∥ transpose stripe ts -------------
// blocks [0, gblocks): gather, class c=bid%8 (XCD), R14 balanced schedule
//   within the stripe (npb_s point-blocks per level per stripe).
// blocks [gblocks, gblocks+npb_s*8): transpose of stripe ts.
__global__ __launch_bounds__(TPB) void hashenc_pipe(
    const float* __restrict__ coords,
    const float* __restrict__ tables,
    uint32_t* __restrict__ ws,
    float* __restrict__ out,
    int npts, int gs, int ts, int gblocks, int npb_s)
{
    constexpr int RESI[16] = RESI_LIST;
    constexpr int SIZ[16] = SIZ_LIST;

    __shared__ float buf[128 * 33];

    const int t = threadIdx.x;

    if ((int)blockIdx.x < gblocks) {
        // ---------------- gather part (stripe gs) ----------------
        const int c = blockIdx.x & 7;
        const long long k = blockIdx.x >> 3;
        const long long off = (long long)gs * npb_s;

        if (k < npb_s) {
            const long long pb = off + k;
            switch (c) {   // wave-uniform, compile-time bodies
                case 0: gather_body<5>(coords, tables, ws, npts, pb, t); break;
                case 1: gather_body<6>(coords, tables, ws, npts, pb, t); break;
                case 2: gather_body<7>(coords, tables, ws, npts, pb, t); break;
                case 3: gather_body<8>(coords, tables, ws, npts, pb, t); break;
                case 4: gather_body<9>(coords, tables, ws, npts, pb, t); break;
                case 5: gather_body<10>(coords, tables, ws, npts, pb, t); break;
                case 6: gather_body<11>(coords, tables, ws, npts, pb, t); break;
                case 7: gather_body<12>(coords, tables, ws, npts, pb, t); break;
            }
        } else {
            const long long per_class = (3LL * npb_s + 7) >> 3;
            const long long ti = (long long)c * per_class + (k - npb_s);
            if (ti < 3LL * npb_s) {
                const long long pb = off + ti % npb_s;
                switch ((int)(ti / npb_s)) {
                    case 0: gather_body<13>(coords, tables, ws, npts, pb, t); break;
                    case 1: gather_body<14>(coords, tables, ws, npts, pb, t); break;
                    case 2: gather_body<15>(coords, tables, ws, npts, pb, t); break;
                }
            }
        }
        return;
    }

    // ---------------- transpose part (stripe ts) ----------------
    const int tb = (int)blockIdx.x - gblocks;
    const long long pbase = ((long long)ts * npb_s * 8 + tb) * 256;
    const long long p = pbase + t;

    const float cx = coords[3 * p + 0];
    const float cy = coords[3 * p + 1];
    const float cz = coords[3 * p + 2];

    vfloat2 feat[16];
#pragma unroll
    for (int l = 0; l < 5; ++l) {   // inline coarse gathers (2.47MB tables)
        const uint32_t idx = hash_idx(cx, cy, cz, RESI[l], SIZ[l]);
        feat[l] = *reinterpret_cast<const vfloat2*>(
            tables + ((size_t)l << 20) + ((size_t)idx << 1));
    }
#pragma unroll
    for (int l = 5; l < 16; ++l) {  // fine levels from packed ws (NT)
        const uint32_t v = __builtin_nontemporal_load(
            ws + (size_t)(l - 5) * npts + p);
        feat[l] = unpack_h2(v);
    }

    float* oblk = out + pbase * 32;
#pragma unroll
    for (int h = 0; h < 2; ++h) {
        if ((t >> 7) == h) {
            const int r = t & 127;
#pragma unroll
            for (int l = 0; l < 16; ++l) {
                buf[r * 33 + 2 * l + 0] = feat[l].x;
                buf[r * 33 + 2 * l + 1] = feat[l].y;
            }
        }
        __syncthreads();
#pragma unroll
        for (int k = 0; k < 4; ++k) {
            const int f = k * 1024 + t * 4;
            const int row = f >> 5;
            const int col = f & 31;
            const vfloat4 v = *reinterpret_cast<const vfloat4*>(&buf[row * 33 + col]);
            __builtin_nontemporal_store(v,
                reinterpret_cast<vfloat4*>(&oblk[(long long)h * 4096 + f]));
        }
        __syncthreads();
    }
}

// ---- Fallback: R6 single-phase (ws too small / odd N) ---------------------
__global__ __launch_bounds__(TPB) void hashenc_kernel(
    const float* __restrict__ coords,
    const float* __restrict__ tables,
    float* __restrict__ out,
    int npts)
{
    constexpr int RESI[16] = RESI_LIST;
    constexpr int SIZ[16] = SIZ_LIST;

    __shared__ float buf[128 * 33];

    const int t = threadIdx.x;
    const long long pbase = (long long)blockIdx.x * TPB;
    const long long p = pbase + t;

    const float cx = coords[3 * p + 0];
    const float cy = coords[3 * p + 1];
    const float cz = coords[3 * p + 2];

    float2 feat[16];
#pragma unroll
    for (int l = 0; l < 16; ++l) {
        const uint32_t idx = hash_idx(cx, cy, cz, RESI[l], SIZ[l]);
        feat[l] = *reinterpret_cast<const float2*>(
            tables + ((size_t)l << 20) + ((size_t)idx << 1));
    }

    float* oblk = out + pbase * 32;
#pragma unroll
    for (int h = 0; h < 2; ++h) {
        if ((t >> 7) == h) {
            const int r = t & 127;
#pragma unroll
            for (int l = 0; l < 16; ++l) {
                buf[r * 33 + 2 * l + 0] = feat[l].x;
                buf[r * 33 + 2 * l + 1] = feat[l].y;
            }
        }
        __syncthreads();
#pragma unroll
        for (int k = 0; k < 4; ++k) {
            const int f = k * 1024 + t * 4;
            const int row = f >> 5;
            const int col = f & 31;
            const vfloat4 v = *reinterpret_cast<const vfloat4*>(&buf[row * 33 + col]);
            __builtin_nontemporal_store(v,
                reinterpret_cast<vfloat4*>(&oblk[(long long)h * 4096 + f]));
        }
        __syncthreads();
    }
}

extern "C" void kernel_launch(void* const* d_in, const int* in_sizes, int n_in,
                              void* d_out, int out_size, void* d_ws, size_t ws_size,
                              hipStream_t stream)
{
    const float* coords = (const float*)d_in[0];
    const float* tables = (const float*)d_in[1];
    float* out = (float*)d_out;
    const int npts = in_sizes[0] / 3;   // 2^21

    const int S = 4;
    const size_t need = (size_t)11 * (size_t)npts * sizeof(uint32_t);
    if (ws_size >= need && (npts % (2048 * S)) == 0) {
        uint32_t* ws = (uint32_t*)d_ws;
        const int npb_s = npts / 2048 / S;                 // pt-blocks/stripe
        const int per_class_s = (3 * npb_s + 7) / 8;
        const int gblocks = 8 * (npb_s + per_class_s);
        const int tblocks = npb_s * 8;
        for (int i = 0; i <= S; ++i) {
            const int gs = (i < S) ? i : -1;       // gather stripe (or none)
            const int ts = i - 1;                  // transpose stripe (or none)
            const int gb = (gs >= 0) ? gblocks : 0;
            const int tb = (ts >= 0) ? tblocks : 0;
            hipLaunchKernelGGL(hashenc_pipe, dim3(gb + tb), dim3(TPB), 0, stream,
                               coords, tables, ws, out, npts, gs, ts, gb, npb_s);
        }
    } else {
        hipLaunchKernelGGL(hashenc_kernel, dim3(npts / TPB), dim3(TPB), 0, stream,
                           coords, tables, out, npts);
    }
}

// Round 18
// 277.500 us; speedup vs baseline: 1.0910x; 1.0910x over previous
//
#include <hip/hip_runtime.h>
#include <hip/hip_fp16.h>
#include <stdint.h>

// MultiResolutionHashEncoding — R18: R16 structure, regular (cached) ws
// loads in transpose.
//
// R16: 274us = gather 160 + transpose ~110. R17 stripe-pipeline: 303us
//   (REGRESSION — launch ramps + L2 contention; overlap dead, reverted).
// R18: R7's pure transpose hit 5.8TB/s with REGULAR ws loads; R16's runs
//   3.5TB/s with NT ws loads. R15 proved NT loads take the uncached
//   long-latency path on gfx950. Fix: regular ws loads (keep NT output
//   stores, keep NT ws stores in gather — those protect table L2
//   residency).
// Prediction: transpose 110 -> 90-100, total -> ~258-268us. If transpose
//   unmoved: remaining gap is coarse-gather latency; we're ~5% from the
//   structural floor (gather request-service ~150 + transpose ~95).

#define TPB 256

typedef float vfloat4 __attribute__((ext_vector_type(4)));
typedef float vfloat2 __attribute__((ext_vector_type(2)));

__device__ __forceinline__ uint32_t hash_idx(float cx, float cy, float cz,
                                             int resi, int siz)
{
    const float rf = (float)resi;
    const int x = (int)floorf(cx * rf);
    const int y = (int)floorf(cy * rf);
    const int z = (int)floorf(cz * rf);
    // int32 wraparound multiplies + xor (uint32 = UB-free)
    const uint32_t h = (uint32_t)x * 73856093u
                     ^ (uint32_t)y * 19349663u
                     ^ (uint32_t)z * 83492791u;
    const int32_t hs = (int32_t)h;
    if (siz == (1 << 19)) {
        // numpy abs(INT_MIN)=INT_MIN; python-mod 2^19 == mask
        const uint32_t a = (hs < 0) ? (0u - h) : h;
        return a & 0x7FFFFu;
    } else {
        int32_t a = (hs < 0) ? (int32_t)(0u - h) : hs;
        int32_t r = a % siz;          // compile-time divisor -> magic mul
        if (r < 0) r += siz;
        return (uint32_t)r;
    }
}

__device__ __forceinline__ uint32_t pack_h2(float a, float b)
{
    const __half ha = __float2half_rn(a);
    const __half hb = __float2half_rn(b);
    return (uint32_t)__half_as_ushort(ha)
         | ((uint32_t)__half_as_ushort(hb) << 16);
}

__device__ __forceinline__ vfloat2 unpack_h2(uint32_t v)
{
    vfloat2 r;
    r.x = __half2float(__ushort_as_half((uint16_t)(v & 0xFFFFu)));
    r.y = __half2float(__ushort_as_half((uint16_t)(v >> 16)));
    return r;
}

#define RESI_LIST {16, 22, 30, 42, 58, 80, 111, 153, \
                   212, 294, 406, 561, 776, 1072, 1482, 2048}
#define SIZ_LIST  {4096, 10648, 27000, 74088, 195112, 512000, \
                   524288, 524288, 524288, 524288, 524288, \
                   524288, 524288, 524288, 524288, 524288}

// ---- compile-time per-level gather body: point-block pb (2048 pts) --------
// ws: packed half2, one uint32 per (level, point).
template<int LV>
__device__ __forceinline__ void gather_body(
    const float* __restrict__ coords,
    const float* __restrict__ tables,
    uint32_t* __restrict__ ws,
    int npts, long long pb, int t)
{
    constexpr int RESI[16] = RESI_LIST;
    constexpr int SIZ[16] = SIZ_LIST;

    const long long base = pb * 2048;
    const float* tab = tables + ((size_t)LV << 20);

    uint32_t g[8];
#pragma unroll
    for (int j = 0; j < 8; ++j) {
        const long long p = base + j * 256 + t;
        const float cx = coords[3 * p + 0];   // regular loads (R15 lesson)
        const float cy = coords[3 * p + 1];
        const float cz = coords[3 * p + 2];
        const uint32_t idx = hash_idx(cx, cy, cz, RESI[LV], SIZ[LV]);
        const vfloat2 f = *reinterpret_cast<const vfloat2*>(
            tab + ((size_t)idx << 1));
        g[j] = pack_h2(f.x, f.y);
    }
    uint32_t* wl = ws + (size_t)(LV - 5) * npts + base;
#pragma unroll
    for (int j = 0; j < 8; ++j)   // NT: don't evict the L2-hot table
        __builtin_nontemporal_store(g[j], wl + j * 256 + t);
}

// ---- single balanced gather launch ----------------------------------------
// class c = bid%8 (XCD): k<npb -> primary level 5+c, pb=k;
// else tail unit ti = c*per_class + (k-npb) in [0,3*npb):
//   level = 13 + ti/npb, pb = ti%npb. Sequential per XCD.
__global__ __launch_bounds__(TPB) void hashenc_gather_merged(
    const float* __restrict__ coords,
    const float* __restrict__ tables,
    uint32_t* __restrict__ ws,
    int npts)
{
    const int t = threadIdx.x;
    const int c = blockIdx.x & 7;
    const long long k = blockIdx.x >> 3;
    const long long npb = (long long)npts >> 11;   // npts/2048

    if (k < npb) {
        switch (c) {   // wave-uniform, compile-time bodies
            case 0: gather_body<5>(coords, tables, ws, npts, k, t); break;
            case 1: gather_body<6>(coords, tables, ws, npts, k, t); break;
            case 2: gather_body<7>(coords, tables, ws, npts, k, t); break;
            case 3: gather_body<8>(coords, tables, ws, npts, k, t); break;
            case 4: gather_body<9>(coords, tables, ws, npts, k, t); break;
            case 5: gather_body<10>(coords, tables, ws, npts, k, t); break;
            case 6: gather_body<11>(coords, tables, ws, npts, k, t); break;
            case 7: gather_body<12>(coords, tables, ws, npts, k, t); break;
        }
    } else {
        const long long per_class = (3 * npb + 7) >> 3;
        const long long ti = (long long)c * per_class + (k - npb);
        if (ti < 3 * npb) {
            const long long pb = ti % npb;
            switch ((int)(ti / npb)) {
                case 0: gather_body<13>(coords, tables, ws, npts, pb, t); break;
                case 1: gather_body<14>(coords, tables, ws, npts, pb, t); break;
                case 2: gather_body<15>(coords, tables, ws, npts, pb, t); break;
            }
        }
    }
}

// ---- Phase 2: coarse gather (levels 0-4, tables 2.47MB = L2-hot)
//      + transpose packed ws fine levels -> out (N,32) ---------------------
__global__ __launch_bounds__(TPB) void hashenc_transpose_fused(
    const float* __restrict__ coords,
    const float* __restrict__ tables,
    const uint32_t* __restrict__ ws,
    float* __restrict__ out,
    int npts)
{
    constexpr int RESI[16] = RESI_LIST;
    constexpr int SIZ[16] = SIZ_LIST;

    __shared__ float buf[128 * 33];

    const int t = threadIdx.x;
    const long long pbase = (long long)blockIdx.x * TPB;
    const long long p = pbase + t;

    const float cx = coords[3 * p + 0];
    const float cy = coords[3 * p + 1];
    const float cz = coords[3 * p + 2];

    vfloat2 feat[16];
#pragma unroll
    for (int l = 0; l < 5; ++l) {   // inline coarse gathers (hot tables, exact f32)
        const uint32_t idx = hash_idx(cx, cy, cz, RESI[l], SIZ[l]);
        feat[l] = *reinterpret_cast<const vfloat2*>(
            tables + ((size_t)l << 20) + ((size_t)idx << 1));
    }
#pragma unroll
    for (int l = 5; l < 16; ++l) {  // fine levels from packed ws — REGULAR
        const uint32_t v = ws[(size_t)(l - 5) * npts + p];   // cached loads
        feat[l] = unpack_h2(v);
    }

    float* oblk = out + pbase * 32;
#pragma unroll
    for (int h = 0; h < 2; ++h) {
        if ((t >> 7) == h) {
            const int r = t & 127;
#pragma unroll
            for (int l = 0; l < 16; ++l) {
                buf[r * 33 + 2 * l + 0] = feat[l].x;
                buf[r * 33 + 2 * l + 1] = feat[l].y;
            }
        }
        __syncthreads();
#pragma unroll
        for (int k = 0; k < 4; ++k) {
            const int f = k * 1024 + t * 4;
            const int row = f >> 5;
            const int col = f & 31;
            const vfloat4 v = *reinterpret_cast<const vfloat4*>(&buf[row * 33 + col]);
            __builtin_nontemporal_store(v,
                reinterpret_cast<vfloat4*>(&oblk[(long long)h * 4096 + f]));
        }
        __syncthreads();
    }
}

// ---- Fallback: R6 single-phase (ws too small / odd N) ---------------------
__global__ __launch_bounds__(TPB) void hashenc_kernel(
    const float* __restrict__ coords,
    const float* __restrict__ tables,
    float* __restrict__ out,
    int npts)
{
    constexpr int RESI[16] = RESI_LIST;
    constexpr int SIZ[16] = SIZ_LIST;

    __shared__ float buf[128 * 33];

    const int t = threadIdx.x;
    const long long pbase = (long long)blockIdx.x * TPB;
    const long long p = pbase + t;

    const float cx = coords[3 * p + 0];
    const float cy = coords[3 * p + 1];
    const float cz = coords[3 * p + 2];

    float2 feat[16];
#pragma unroll
    for (int l = 0; l < 16; ++l) {
        const uint32_t idx = hash_idx(cx, cy, cz, RESI[l], SIZ[l]);
        feat[l] = *reinterpret_cast<const float2*>(
            tables + ((size_t)l << 20) + ((size_t)idx << 1));
    }

    float* oblk = out + pbase * 32;
#pragma unroll
    for (int h = 0; h < 2; ++h) {
        if ((t >> 7) == h) {
            const int r = t & 127;
#pragma unroll
            for (int l = 0; l < 16; ++l) {
                buf[r * 33 + 2 * l + 0] = feat[l].x;
                buf[r * 33 + 2 * l + 1] = feat[l].y;
            }
        }
        __syncthreads();
#pragma unroll
        for (int k = 0; k < 4; ++k) {
            const int f = k * 1024 + t * 4;
            const int row = f >> 5;
            const int col = f & 31;
            const vfloat4 v = *reinterpret_cast<const vfloat4*>(&buf[row * 33 + col]);
            __builtin_nontemporal_store(v,
                reinterpret_cast<vfloat4*>(&oblk[(long long)h * 4096 + f]));
        }
        __syncthreads();
    }
}

extern "C" void kernel_launch(void* const* d_in, const int* in_sizes, int n_in,
                              void* d_out, int out_size, void* d_ws, size_t ws_size,
                              hipStream_t stream)
{
    const float* coords = (const float*)d_in[0];
    const float* tables = (const float*)d_in[1];
    float* out = (float*)d_out;
    const int npts = in_sizes[0] / 3;   // 2^21

    const size_t need = (size_t)11 * (size_t)npts * sizeof(uint32_t);
    if (ws_size >= need && (npts % 2048) == 0) {
        uint32_t* ws = (uint32_t*)d_ws;
        const long long npb = npts / 2048;
        const long long per_class = (3 * npb + 7) / 8;
        const dim3 g((unsigned)(8 * (npb + per_class))), b(TPB);
        hipLaunchKernelGGL(hashenc_gather_merged, g, b, 0, stream,
                           coords, tables, ws, npts);
        hipLaunchKernelGGL(hashenc_transpose_fused, dim3(npts / TPB), b, 0, stream,
                           coords, tables, (const uint32_t*)d_ws, out, npts);
    } else {
        hipLaunchKernelGGL(hashenc_kernel, dim3(npts / TPB), dim3(TPB), 0, stream,
                           coords, tables, out, npts);
    }
}